// Round 6
// baseline (50.765 us; speedup 1.0000x reference)
//
#include <hip/hip_runtime.h>

typedef __attribute__((ext_vector_type(8))) short short8;
typedef __attribute__((ext_vector_type(4))) float f32x4;

#define CI    128
#define CO_   256
#define HW_   56
#define PLANE 3136
#define NB    16
#define STOT  50176
#define KTOT  1152
#define OUTN  802816   // CO_*PLANE

// ws layout: [0, 12845056) Xt bf16 NHWC ; [12845056, +589824) Wpre bf16 ; then 256B zeros
#define XT_BYTES   12845056ull
#define WP_USHORTS 294912
#define WS_NEED    (12845056ull + 589824ull + 256ull)

__device__ __forceinline__ unsigned short f2bf(float f) {
  unsigned u = __float_as_uint(f);
  u += 0x7FFFu + ((u >> 16) & 1u);   // RNE
  return (unsigned short)(u >> 16);
}

__device__ __forceinline__ void gload16(void* lds, const void* g) {
  __builtin_amdgcn_global_load_lds(
      (const __attribute__((address_space(1))) unsigned int*)g,
      (__attribute__((address_space(3))) unsigned int*)lds, 16, 0, 0);
}

template <int N> __device__ __forceinline__ void vmwait() {
  asm volatile("s_waitcnt vmcnt(%0)" ::"n"(N) : "memory");
}

// ---------------- fused prep: blocks 0..1599 = prep_x ; 1600..1743 = prep_w ----------------
__global__ __launch_bounds__(256) void prep_fused(const float* __restrict__ X,
                                                  const float* __restrict__ W,
                                                  unsigned short* __restrict__ Xt,
                                                  unsigned short* __restrict__ Wp) {
  const int t = threadIdx.x;
  if (blockIdx.x < 1600) {
    // ---- prep_x: NCHW fp32 -> NHWC bf16 (tiled transpose)
    __shared__ __align__(16) unsigned short tile[32][132];
    const int bx = blockIdx.x;
    const int n   = bx / 100;
    const int rem = bx % 100;
    const int cib = rem / 25;
    const int spb = rem % 25;
    const int sp0 = spb * 128;
    const float* src = X + (size_t)(n * CI + cib * 32) * PLANE;
#pragma unroll
    for (int j = 0; j < 4; ++j) {
      int f = t + 256 * j;
      int ci  = f >> 5;
      int sp4 = (f & 31) * 4;
      if (sp0 + sp4 < PLANE) {
        f32x4 v = *(const f32x4*)(src + (size_t)ci * PLANE + sp0 + sp4);
#pragma unroll
        for (int e = 0; e < 4; ++e) tile[ci][sp4 + e] = f2bf(v[e]);
      }
    }
    __syncthreads();
    unsigned short* dst = Xt + ((size_t)n * PLANE + sp0) * CI + cib * 32;
#pragma unroll
    for (int j = 0; j < 2; ++j) {
      int g = t + 256 * j;
      int sp = g >> 2;
      int q  = g & 3;
      if (sp0 + sp < PLANE) {
        short8 v;
#pragma unroll
        for (int e = 0; e < 8; ++e) v[e] = (short)tile[q * 8 + e][sp];
        *(short8*)(dst + (size_t)sp * CI + q * 8) = v;
      }
    }
  } else {
    // ---- prep_w: OIHW fp32 -> Wpre, R3-proven layout:
    // sub-tile s=(r*4+cb) occupies s*16KB; chunk c (0..1023): co=c>>2,
    // granule holds ci-group kg=(c&3)^((c>>3)&3): ci = cb*32+kg*8+e, tap r.
    const int u = (blockIdx.x - 1600) * 256 + t;   // 0..36863
    const int rcbmt = u >> 9;          // 0..71 = ((r*4+cb)*2+half)
    const int p     = u & 511;
    const int mt  = rcbmt & 1;
    const int rcb = rcbmt >> 1;        // 0..35
    const int cb  = rcb & 3;
    const int r   = rcb >> 2;          // 0..8
    const int col = p >> 2;            // co_local 0..127
    const int kg  = (p & 3) ^ ((col >> 1) & 3);
    const int co  = mt * 128 + col;
    const int ci0 = cb * 32 + kg * 8;
    short8 v;
#pragma unroll
    for (int e = 0; e < 8; ++e)
      v[e] = (short)f2bf(W[(size_t)co * KTOT + (size_t)(ci0 + e) * 9 + r]);
    *(short8*)(Wp + (size_t)u * 8) = v;
    if (u < 16) {
      short8 z = {0, 0, 0, 0, 0, 0, 0, 0};
      *(short8*)(Wp + WP_USHORTS + u * 8) = z;
    }
  }
}

// ---------------- conv_gemm: 256x256 tile, 8 waves, 4-deep ring, counted vmcnt ----------------
// Per sub-step (K=32): vmwait(4); barrier; stage(s+3); read bF[0..3] FIRST, then per m-group
// {read aF[m]; 4 MFMA} -- drip-feed order so the first MFMA needs only 5 of 12 reads and each
// subsequent LDS return (12cy) unlocks 19.4cy of matrix work (matrix-bound steady state).
// grid 196 sp-tiles of 256 ; block 512 = 8 waves (2M x 4N), wave tile 128co x 64sp
__global__ __launch_bounds__(512, 2) void conv_gemm(const unsigned short* __restrict__ Xt,
                                                    const unsigned short* __restrict__ Wp,
                                                    const float* __restrict__ bias,
                                                    float* __restrict__ out) {
  __shared__ __align__(1024) char smem[131072];  // ring of 4 x (A 16K | B 16K)
  const int t    = threadIdx.x;
  const int lane = t & 63;
  const int wid  = t >> 6;
  const int wm   = wid >> 2, wn = wid & 3;

  // bijective XCD swizzle for 196 blocks (q=24, r=4)
  const int orig = blockIdx.x;
  const int xcd = orig & 7, idx = orig >> 3;
  const int spt = (xcd < 4 ? xcd * 25 : 100 + (xcd - 4) * 24) + idx;   // 0..195

  // --- staging precompute: thread t covers B rows S0 (half 0) and S1 (half 1)
  const int kgB = (t & 3) ^ ((t >> 3) & 3);
  const int S0 = spt * 256 + (t >> 2);
  const int S1 = S0 + 128;
  const int hw0 = S0 % PLANE, h0 = hw0 / HW_, w0 = hw0 - h0 * HW_;
  const int hw1 = S1 % PLANE, h1 = hw1 / HW_, w1 = hw1 - h1 * HW_;
  int vm0 = 0, vm1 = 0;
#pragma unroll
  for (int r = 0; r < 9; ++r) {
    int dh = r / 3 - 1, dw = r % 3 - 1;
    vm0 |= (int)(((unsigned)(h0 + dh) < HW_) & ((unsigned)(w0 + dw) < HW_)) << r;
    vm1 |= (int)(((unsigned)(h1 + dh) < HW_) & ((unsigned)(w1 + dw) < HW_)) << r;
  }
  const char* xb0 = (const char*)Xt + ((size_t)S0 * CI + kgB * 8) * 2;
  const char* xb1 = (const char*)Xt + ((size_t)S1 * CI + kgB * 8) * 2;
  const char* zb  = (const char*)(Wp + WP_USHORTS) + (t & 3) * 16;
  const char* wpA = (const char*)Wp + t * 16;

  // fragment read offsets (64B rows, granule swizzle q^((row>>1)&3), lane-constant)
  const int swz  = ((lane >> 4) ^ ((lane >> 1) & 3)) * 16;
  const int aoff = (wm * 128 + (lane & 15)) * 64 + swz;           // + m*1024
  const int boff = 16384 + (wn * 64 + (lane & 15)) * 64 + swz;    // + n*1024

  f32x4 acc[8][4];
  const f32x4 zf = {0.f, 0.f, 0.f, 0.f};
#pragma unroll
  for (int m = 0; m < 8; ++m)
#pragma unroll
    for (int n = 0; n < 4; ++n) acc[m][n] = zf;

  auto SA = [&](int s1, int j, char* buf) {
    gload16(buf + j * 8192 + wid * 1024, wpA + (size_t)s1 * 16384 + j * 8192);
  };
  auto SB = [&](int s1, int j, char* buf) {
    const int r = s1 >> 2, cb = s1 & 3;
    const int dh = r / 3 - 1, dw = r % 3 - 1;
    const int ro = dh * HW_ + dw;
    const bool v = ((j ? vm1 : vm0) >> r) & 1;
    const char* src = (j ? xb1 : xb0) + ro * 256 + cb * 64;
    gload16(buf + 16384 + j * 8192 + wid * 1024, v ? src : zb);
  };
  auto STAGE = [&](int s1) {
    char* nb = smem + (s1 & 3) * 32768;
    SA(s1, 0, nb); SA(s1, 1, nb); SB(s1, 0, nb); SB(s1, 1, nb);
  };

  // prologue: 3 sub-tiles in flight
  STAGE(0); STAGE(1); STAGE(2);

#pragma unroll
  for (int s = 0; s < 36; ++s) {
    // counted wait: certifies stage(s) [and stage(s+1) from s>=1]; never drains to 0 mid-loop.
    if (s <= 34) vmwait<4>();
    else         vmwait<0>();
    __builtin_amdgcn_s_barrier();      // stage-s data visible to all; all waves past s-1 reads

    if (s <= 32) STAGE(s + 3);         // overwrite buf last read at s-1 (safe post-barrier)

    const char* rb = smem + (s & 3) * 32768;
    short8 bF[4];
#pragma unroll
    for (int n = 0; n < 4; ++n) bF[n] = *(const short8*)(rb + boff + n * 1024);

    __builtin_amdgcn_s_setprio(1);
#pragma unroll
    for (int m = 0; m < 8; ++m) {
      short8 aFm = *(const short8*)(rb + aoff + m * 1024);   // drip: 1 read unlocks 4 MFMA
#pragma unroll
      for (int n = 0; n < 4; ++n)
        acc[m][n] = __builtin_amdgcn_mfma_f32_16x16x32_bf16(aFm, bF[n], acc[m][n], 0, 0, 0);
    }
    __builtin_amdgcn_s_setprio(0);
  }

  // ---- epilogue: D row = co = (lane>>4)*4+reg, col = sp = lane&15
#pragma unroll
  for (int nf = 0; nf < 4; ++nf) {
    int S = spt * 256 + wn * 64 + nf * 16 + (lane & 15);
    int nimg = S / PLANE, hw = S - nimg * PLANE;
    float* ob = out + (size_t)nimg * OUTN + hw;
#pragma unroll
    for (int mf = 0; mf < 8; ++mf) {
      int cob = wm * 128 + mf * 16 + (lane >> 4) * 4;
#pragma unroll
      for (int r2 = 0; r2 < 4; ++r2)
        ob[(size_t)(cob + r2) * PLANE] = acc[mf][nf][r2] + bias[cob + r2];
    }
  }
}

// ---------------- fallback: naive direct conv (only if ws too small) ----------------
__global__ __launch_bounds__(256) void conv_naive(const float* __restrict__ X,
                                                  const float* __restrict__ W,
                                                  const float* __restrict__ bias,
                                                  float* __restrict__ out) {
  int idx = blockIdx.x * 256 + threadIdx.x;
  int hw = idx % PLANE;
  int co = (idx / PLANE) & 255;
  int n  = idx / (PLANE * 256);
  int h = hw / HW_, w = hw - h * HW_;
  float acc = bias[co];
  const float* xp = X + (size_t)n * CI * PLANE;
  const float* wp = W + (size_t)co * KTOT;
  for (int ci = 0; ci < CI; ++ci) {
#pragma unroll
    for (int kh = 0; kh < 3; ++kh) {
      int y = h + kh - 1;
      if ((unsigned)y >= HW_) continue;
#pragma unroll
      for (int kw = 0; kw < 3; ++kw) {
        int x = w + kw - 1;
        if ((unsigned)x >= HW_) continue;
        acc += xp[(size_t)ci * PLANE + y * HW_ + x] * wp[ci * 9 + kh * 3 + kw];
      }
    }
  }
  out[idx] = acc;
}

extern "C" void kernel_launch(void* const* d_in, const int* in_sizes, int n_in,
                              void* d_out, int out_size, void* d_ws, size_t ws_size,
                              hipStream_t stream) {
  (void)in_sizes; (void)n_in; (void)out_size;
  const float* X = (const float*)d_in[0];
  const float* W = (const float*)d_in[1];
  const float* b = (const float*)d_in[2];
  float* out = (float*)d_out;
  if (ws_size >= WS_NEED) {
    unsigned short* Xt = (unsigned short*)d_ws;
    unsigned short* Wp = (unsigned short*)((char*)d_ws + XT_BYTES);
    prep_fused<<<1744, 256, 0, stream>>>(X, W, Xt, Wp);
    conv_gemm<<<196, 512, 0, stream>>>(Xt, Wp, b, out);
  } else {
    conv_naive<<<(NB * CO_ * PLANE + 255) / 256, 256, 0, stream>>>(X, W, b, out);
  }
}